// Round 11
// baseline (204.100 us; speedup 1.0000x reference)
//
#include <hip/hip_runtime.h>
#include <hip/hip_fp16.h>
#include <cmath>

#define BATCH 1024
#define SOUT 36336
#define POUT 10596
#define PS_COLS 10464   // s params compacted (dec2 block removed)
#define PP_COLS 10596
#define PD_COLS 25872   // s dec2 block (W 32x784 + b 784)
#define PD_TILES 405    // ceil(25872/64)

typedef __attribute__((ext_vector_type(8))) short bf16x8;
typedef __attribute__((ext_vector_type(4))) float f32x4;

__device__ __forceinline__ float sigmoidf_(float x){ return 1.0f/(1.0f+__expf(-x)); }
__device__ __forceinline__ float reluf_(float x){ return x>0.0f?x:0.0f; }

__device__ __forceinline__ void bf16split(float f, unsigned short& hi, unsigned short& lo){
  unsigned u = __float_as_uint(f);
  hi = (unsigned short)(u >> 16);
  float fhi = __uint_as_float(((unsigned)hi) << 16);
  float rem = f - fhi;                       // exact in fp32
  lo = (unsigned short)(__float_as_uint(rem) >> 16);
}

// ---------------- K1: backbone hidden h2 (s and p), emitted as bf16 hi/lo ---------
__global__ __launch_bounds__(128) void k_backbone(
    const float* __restrict__ z,
    const float* __restrict__ sw1, const float* __restrict__ sb1,
    const float* __restrict__ sw2, const float* __restrict__ sb2,
    const float* __restrict__ pw1, const float* __restrict__ pb1,
    const float* __restrict__ pw2, const float* __restrict__ pb2,
    unsigned short* __restrict__ h2s_hi, unsigned short* __restrict__ h2s_lo,
    unsigned short* __restrict__ h2p_hi, unsigned short* __restrict__ h2p_lo)
{
  __shared__ float zsh[32];
  __shared__ float h1sh[2][64];
  const int b = blockIdx.x;
  const int tid = threadIdx.x;
  const int g = tid >> 6, o = tid & 63;
  if (tid < 32) zsh[tid] = z[b*32 + tid];
  __syncthreads();
  const float* w1 = g ? pw1 : sw1;
  const float* b1 = g ? pb1 : sb1;
  float acc = b1[o];
  #pragma unroll
  for (int i=0;i<32;i++) acc += zsh[i]*w1[i*64+o];
  h1sh[g][o] = reluf_(acc);
  __syncthreads();
  const float* w2 = g ? pw2 : sw2;
  const float* b2 = g ? pb2 : sb2;
  float acc2 = b2[o];
  #pragma unroll
  for (int i=0;i<64;i++) acc2 += h1sh[g][i]*w2[i*64+o];
  float v = reluf_(acc2);
  unsigned short hi, lo;
  bf16split(v, hi, lo);
  (g ? h2p_hi : h2s_hi)[b*64+o] = hi;
  (g ? h2p_lo : h2s_lo)[b*64+o] = lo;
}

// ---------------- GEMM device body (MFMA, bf16 hi/lo split) ----------------
template <typename OT>
__device__ __forceinline__ void gemm_tile(
    unsigned char* smem,
    const unsigned short* __restrict__ ahi, const unsigned short* __restrict__ alo,
    const float* __restrict__ w3, const float* __restrict__ b3,
    OT* __restrict__ outp, int OC, int thr, int off, int stride, int xt)
{
  unsigned short (*wth)[72] = reinterpret_cast<unsigned short(*)[72]>(smem);
  unsigned short (*wtl)[72] = reinterpret_cast<unsigned short(*)[72]>(smem + 9216);
  const int c0 = xt*64;
  const int tid = threadIdx.x;

  for (int idx=tid; idx<4096; idx+=256){
    int j = idx >> 6, cc = idx & 63;
    int c = c0 + cc; if (c > OC-1) c = OC-1;
    int src = (c < thr) ? c : c + off;
    float f = w3[(size_t)j*stride + src];
    unsigned short hi, lo;
    bf16split(f, hi, lo);
    wth[cc][j] = hi; wtl[cc][j] = lo;
  }
  __syncthreads();

  const int wv = tid >> 6, l = tid & 63;
  const int lr = l & 15, lq = l >> 4;

  bf16x8 Bh[2][4], Bl[2][4];
  #pragma unroll
  for (int ks=0; ks<2; ks++){
    #pragma unroll
    for (int ct=0; ct<4; ct++){
      const int row = ct*16 + lr;
      const int joff = ks*32 + lq*8;
      Bh[ks][ct] = *reinterpret_cast<const bf16x8*>(&wth[row][joff]);
      Bl[ks][ct] = *reinterpret_cast<const bf16x8*>(&wtl[row][joff]);
    }
  }
  float bv[4];
  #pragma unroll
  for (int ct=0; ct<4; ct++){
    int c = c0 + ct*16 + lr; if (c > OC-1) c = OC-1;
    int src = (c < thr) ? c : c + off;
    bv[ct] = b3[src];
  }

  for (int bsub=0; bsub<16; bsub++){
    const int arow = bsub*64 + wv*16 + lr;
    const unsigned short* ah = ahi + arow*64;
    const unsigned short* al = alo + arow*64;
    bf16x8 Ah0 = *reinterpret_cast<const bf16x8*>(ah + lq*8);
    bf16x8 Ah1 = *reinterpret_cast<const bf16x8*>(ah + 32 + lq*8);
    bf16x8 Al0 = *reinterpret_cast<const bf16x8*>(al + lq*8);
    bf16x8 Al1 = *reinterpret_cast<const bf16x8*>(al + 32 + lq*8);
    #pragma unroll
    for (int ct=0; ct<4; ct++){
      f32x4 acc = {0.f,0.f,0.f,0.f};
      acc = __builtin_amdgcn_mfma_f32_16x16x32_bf16(Ah0, Bh[0][ct], acc, 0,0,0);
      acc = __builtin_amdgcn_mfma_f32_16x16x32_bf16(Ah1, Bh[1][ct], acc, 0,0,0);
      acc = __builtin_amdgcn_mfma_f32_16x16x32_bf16(Ah0, Bl[0][ct], acc, 0,0,0);
      acc = __builtin_amdgcn_mfma_f32_16x16x32_bf16(Ah1, Bl[1][ct], acc, 0,0,0);
      acc = __builtin_amdgcn_mfma_f32_16x16x32_bf16(Al0, Bh[0][ct], acc, 0,0,0);
      acc = __builtin_amdgcn_mfma_f32_16x16x32_bf16(Al1, Bh[1][ct], acc, 0,0,0);
      const int c = c0 + ct*16 + lr;
      if (c < OC){
        const int r0 = bsub*64 + wv*16 + lq*4;
        const float bb = bv[ct];
        #pragma unroll
        for (int rr=0; rr<4; rr++){
          float vo = acc[rr] + bb;
          if constexpr (sizeof(OT) == 2)
            outp[(size_t)(r0+rr)*OC + c] = __float2half(vo);
          else
            outp[(size_t)(r0+rr)*OC + c] = vo;
        }
      }
    }
  }
}

// ---------------- K2: Ps + Pp GEMMs (needed before k_seq) ----------------
__global__ __launch_bounds__(256, 2) void k_params5(
    const unsigned short* __restrict__ h2s_hi, const unsigned short* __restrict__ h2s_lo,
    const unsigned short* __restrict__ h2p_hi, const unsigned short* __restrict__ h2p_lo,
    const float* __restrict__ sw3, const float* __restrict__ sb3,
    const float* __restrict__ pw3, const float* __restrict__ pb3,
    float* __restrict__ Ps, float* __restrict__ Pp)
{
  __shared__ __align__(16) unsigned char smem[18432];
  int xt = blockIdx.x;
  if (xt < 164){
    gemm_tile<float>(smem, h2s_hi, h2s_lo, sw3, sb3, Ps, PS_COLS, 4192, 25872, SOUT, xt);
  } else {
    gemm_tile<float>(smem, h2p_hi, h2p_lo, pw3, pb3, Pp, PP_COLS, 0x40000000, 0, POUT, xt-164);
  }
}

// ---------------- K3 (fused): blocks 0..404 = Pd GEMM; 405.. = hyper-GRU seq -------
// GEMM blocks scheduled first -> they drain in a few us and seq blocks backfill.
// Seq: 256 thr/elem, cap 128 VGPR (need ~112) -> 4 blocks/CU -> single round.
__global__ __launch_bounds__(256, 4) void k_seq_pd(
    const unsigned short* __restrict__ h2s_hi, const unsigned short* __restrict__ h2s_lo,
    const float* __restrict__ sw3, const float* __restrict__ sb3,
    __half* __restrict__ Pd,
    const float* __restrict__ Ps, const float* __restrict__ Pp,
    float* __restrict__ Dout, float* __restrict__ Aout)
{
  __shared__ __align__(16) unsigned char smem[18432];

  if (blockIdx.x < PD_TILES){
    gemm_tile<__half>(smem, h2s_hi, h2s_lo, sw3, sb3, Pd, PD_COLS, 0, 4192, SOUT, blockIdx.x);
    return;
  }

  float* F = reinterpret_cast<float*>(smem);
  float* xvT  = F;        // 64
  float* xvI  = F + 64;   // 64
  float* initZ= F + 128;  // 64
  float* hst  = F + 192;  // 64
  float* psA  = F + 256;  // 128
  float* e2s  = F + 384;  // 64
  float* gxs  = F + 448;  // 128
  float* ghs  = F + 576;  // 128
  float* rhs  = F + 704;  // 64
  float* d1s  = F + 768;  // 32

  const int b = blockIdx.x - PD_TILES;
  const int tid = threadIdx.x;
  const int g = tid >> 7, lt = tid & 127;
  const float* Gp = g ? (Pp + (size_t)b*PP_COLS) : (Ps + (size_t)b*PS_COLS);
  const int rnn = g ? 4324 : 4192;

  float wA[32], wB[32], wC[32];
  float bA = 0.f, bB = 0.f;
  {
    int baseA;
    if (lt < 64)       baseA = (lt>>5)*1024 + (lt&31);     // enc1 (64x32), K-half
    else if (lt < 96)  baseA = 2080 + (lt-64);             // enc2 (32x32)
    else               baseA = 3136 + (lt-96);             // dec1 (32x32)
    #pragma unroll
    for (int i=0;i<32;i++) wA[i] = Gp[baseA + i*32];
    if (lt < 32)                  bA = Gp[2048 + lt];
    else if (lt >= 64 && lt < 96) bA = Gp[3104 + (lt-64)];
    else if (lt >= 96)            bA = Gp[4160 + (lt-96)];
    if (lt < 96){
      #pragma unroll
      for (int i=0;i<32;i++) wB[i] = Gp[rnn + i*96 + lt];
      bB = Gp[rnn + 6144 + lt];
      #pragma unroll
      for (int i=0;i<32;i++) wC[i] = Gp[rnn + 3072 + i*96 + lt];
    } else if (g == 1 && lt < 100){
      #pragma unroll
      for (int i=0;i<32;i++) wB[i] = Gp[4192 + i*4 + (lt-96)];
      bB = Gp[4320 + (lt-96)];
    }
  }

  if (tid < 64) hst[tid] = 0.f;
  if (tid < 32) initZ[tid] = Ps[(size_t)b*PS_COLS + 10432 + tid];
  else if (tid < 64) initZ[tid] = Pp[(size_t)b*PP_COLS + 10564 + (tid-32)];
  __syncthreads();
  if (tid < 64) xvT[tid] = initZ[tid];
  __syncthreads();

  auto substep = [&](const float* xv, int aidx, int t16, bool isTop){
    // A: e1 partial sums (lanes 0-63)
    if (lt < 64){
      float a0 = (lt < 32) ? bA : 0.f, a1=0.f, a2=0.f, a3=0.f;
      const float4* x4 = reinterpret_cast<const float4*>(&xv[(lt>>5)*32]);
      #pragma unroll
      for (int i=0;i<8;i++){
        float4 v = x4[i];
        a0 += v.x*wA[4*i+0]; a1 += v.y*wA[4*i+1];
        a2 += v.z*wA[4*i+2]; a3 += v.w*wA[4*i+3];
      }
      psA[g*64 + lt] = (a0+a1)+(a2+a3);
    }
    __syncthreads();
    // B: e2 = relu(e1) @ Wenc2 + b (lanes 64-95)
    if (lt >= 64 && lt < 96){
      float a0=bA, a1=0.f, a2=0.f, a3=0.f;
      const float4* p0 = reinterpret_cast<const float4*>(&psA[g*64]);
      const float4* p1 = reinterpret_cast<const float4*>(&psA[g*64+32]);
      #pragma unroll
      for (int i=0;i<8;i++){
        float4 u = p0[i], v = p1[i];
        a0 += reluf_(u.x+v.x)*wA[4*i+0];
        a1 += reluf_(u.y+v.y)*wA[4*i+1];
        a2 += reluf_(u.z+v.z)*wA[4*i+2];
        a3 += reluf_(u.w+v.w)*wA[4*i+3];
      }
      e2s[g*32 + (lt-64)] = (a0+a1)+(a2+a3);
    }
    __syncthreads();
    // C: gx cols 0-63 + gh (lanes 0-63); xh cols 64-95 (lanes 64-95, reg)
    float xh = 0.f;
    if (lt < 64){
      float x0=bB, x1=0.f, h0=0.f, h1=0.f;
      const float4* e4 = reinterpret_cast<const float4*>(&e2s[g*32]);
      const float4* h4 = reinterpret_cast<const float4*>(&hst[g*32]);
      #pragma unroll
      for (int i=0;i<8;i++){
        float4 u = e4[i], v = h4[i];
        x0 += u.x*wB[4*i+0] + u.z*wB[4*i+2];
        x1 += u.y*wB[4*i+1] + u.w*wB[4*i+3];
        h0 += v.x*wC[4*i+0] + v.z*wC[4*i+2];
        h1 += v.y*wC[4*i+1] + v.w*wC[4*i+3];
      }
      gxs[g*64 + lt] = x0+x1;
      ghs[g*64 + lt] = h0+h1;
    } else if (lt < 96){
      float a0=bB, a1=0.f, a2=0.f, a3=0.f;
      const float4* e4 = reinterpret_cast<const float4*>(&e2s[g*32]);
      #pragma unroll
      for (int i=0;i<8;i++){
        float4 u = e4[i];
        a0 += u.x*wB[4*i+0]; a1 += u.y*wB[4*i+1];
        a2 += u.z*wB[4*i+2]; a3 += u.w*wB[4*i+3];
      }
      xh = (a0+a1)+(a2+a3);
    }
    __syncthreads();
    // DEF: gates + candidate + h-update (lanes 64-95); dec1/dec2 (lanes 96-127)
    if (lt >= 64 && lt < 96){
      int o = lt-64;
      float ho = hst[g*32+o];
      float zg = sigmoidf_(gxs[g*64+o]    + ghs[g*64+o]);
      float rg = sigmoidf_(gxs[g*64+32+o] + ghs[g*64+32+o]);
      rhs[g*32+o] = rg * ho;
      float a0=0.f, a1=0.f, a2=0.f, a3=0.f;
      const float4* r4 = reinterpret_cast<const float4*>(&rhs[g*32]);
      #pragma unroll
      for (int i=0;i<8;i++){
        float4 v = r4[i];
        a0 += v.x*wC[4*i+0]; a1 += v.y*wC[4*i+1];
        a2 += v.z*wC[4*i+2]; a3 += v.w*wC[4*i+3];
      }
      float hh = tanhf(xh + (a0+a1)+(a2+a3));
      float hn = zg*ho + (1.f-zg)*hh;
      hst[g*32+o] = hn;
      if (isTop) xvT[g*32+o] = hn; else xvI[g*32+o] = hn;
    }
    if (isTop && tid < 64) xvI[tid] = initZ[tid];   // inner restarts from inits
    if (lt >= 96 && (g==1 || t16 >= 0)){
      int o = lt-96;
      float a0=bA, a1=0.f, a2=0.f, a3=0.f;
      const float4* h4 = reinterpret_cast<const float4*>(&hst[g*32]);
      #pragma unroll
      for (int i=0;i<8;i++){
        float4 v = h4[i];
        a0 += v.x*wA[4*i+0]; a1 += v.y*wA[4*i+1];
        a2 += v.z*wA[4*i+2]; a3 += v.w*wA[4*i+3];
      }
      float d = reluf_((a0+a1)+(a2+a3));
      if (g == 0) Dout[((size_t)t16*BATCH + b)*32 + o] = d;
      else d1s[o] = d;
    }
    if (g == 1 && lt >= 96 && lt < 100){
      int o = lt-96;
      float a0=bB, a1=0.f, a2=0.f, a3=0.f;
      const float4* d4 = reinterpret_cast<const float4*>(&d1s[0]);
      #pragma unroll
      for (int i=0;i<8;i++){
        float4 v = d4[i];
        a0 += v.x*wB[4*i+0]; a1 += v.y*wB[4*i+1];
        a2 += v.z*wB[4*i+2]; a3 += v.w*wB[4*i+3];
      }
      Aout[((size_t)aidx*BATCH + b)*4 + o] = (a0+a1)+(a2+a3);
    }
    __syncthreads();
  };

  for (int t=0;t<4;t++){
    substep(xvT, t, -1, true);
    for (int k=0;k<4;k++){
      substep(xvI, 4 + t*4 + k, t*4 + k, false);
    }
  }
}

// ---------------- bilinear samplers (fp32 and fp16 LDS images) ----------------
__device__ __forceinline__ float fetchpix(const float* __restrict__ img, int y, int x){
  if ((unsigned)y >= 28u || (unsigned)x >= 28u) return 0.0f;
  return img[y*28 + x];
}
__device__ __forceinline__ float fetchpixh(const __half* __restrict__ img, int y, int x){
  if ((unsigned)y >= 28u || (unsigned)x >= 28u) return 0.0f;
  return __half2float(img[y*28 + x]);
}
#define BILIN_BODY(FETCH) \
  const float stepv = 2.0f/27.0f; \
  float gxv = -1.0f + stepv*(float)c; \
  float gyv = -1.0f + stepv*(float)r; \
  float srcx = (a0 + 1.0f)*gxv + a2; \
  float srcy = (a1 + 1.0f)*gyv + a3; \
  float px = (srcx + 1.0f)*13.5f; \
  float py = (srcy + 1.0f)*13.5f; \
  float x0f = floorf(px), y0f = floorf(py); \
  float wx = px - x0f, wy = py - y0f; \
  int x0 = (int)x0f, y0 = (int)y0f; \
  float v00 = FETCH(img, y0,   x0); \
  float v01 = FETCH(img, y0,   x0+1); \
  float v10 = FETCH(img, y0+1, x0); \
  float v11 = FETCH(img, y0+1, x0+1); \
  return v00*(1.0f-wx)*(1.0f-wy) + v01*wx*(1.0f-wy) \
       + v10*(1.0f-wx)*wy + v11*wx*wy;

__device__ __forceinline__ float bilin(const float* __restrict__ img,
    float a0, float a1, float a2, float a3, int r, int c){ BILIN_BODY(fetchpix) }
__device__ __forceinline__ float bilinh(const __half* __restrict__ img,
    float a0, float a1, float a2, float a3, int r, int c){ BILIN_BODY(fetchpixh) }

// ---------------- K4: fused decode: xhat (fp16 Pd stream) + both composites --------
__global__ __launch_bounds__(256, 4) void k_dec(
    const __half* __restrict__ Pd, const float* __restrict__ Dm,
    const float* __restrict__ Am, float* __restrict__ outp)
{
  extern __shared__ float lds[];
  float*  o0 = lds;                                      // 3136 f32
  float*  Da = lds + 3136;                               // 528
  float*  av = lds + 3664;                               // 80
  __half* xh = reinterpret_cast<__half*>(lds + 3744);    // 16*784 halves (25088 B)
  const int b = blockIdx.x;
  const int tid = threadIdx.x;

  for (int idx=tid; idx<512; idx+=256){
    int t = idx >> 5, i = idx & 31;
    Da[t*33 + i] = Dm[((size_t)t*BATCH + b)*32 + i];
  }
  if (tid < 16) Da[tid*33 + 32] = 1.0f;
  if (tid < 80) av[tid] = Am[((size_t)(tid>>2)*BATCH + b)*4 + (tid&3)];

  float4 acc4[16];
  #pragma unroll
  for (int t=0;t<16;t++) acc4[t] = make_float4(0.f,0.f,0.f,0.f);
  __syncthreads();

  const __half* Pdb = Pd + (size_t)b*PD_COLS;
  #pragma unroll 3
  for (int i=0;i<33;i++){
    const __half* row = Pdb + (i<32 ? i*784 : 25088);
    float4 v = make_float4(0.f,0.f,0.f,0.f);
    if (tid < 196){
      const __half2 h0 = reinterpret_cast<const __half2*>(row)[tid*2];
      const __half2 h1 = reinterpret_cast<const __half2*>(row)[tid*2+1];
      float2 f0 = __half22float2(h0), f1 = __half22float2(h1);
      v = make_float4(f0.x, f0.y, f1.x, f1.y);
    }
    #pragma unroll
    for (int t=0;t<16;t++){
      float da = Da[t*33 + i];
      acc4[t].x += da*v.x; acc4[t].y += da*v.y;
      acc4[t].z += da*v.z; acc4[t].w += da*v.w;
    }
  }
  if (tid < 196){
    #pragma unroll
    for (int t=0;t<16;t++){
      __half2* dst = reinterpret_cast<__half2*>(xh + t*784 + tid*4);
      dst[0] = __floats2half2_rn(acc4[t].x, acc4[t].y);
      dst[1] = __floats2half2_rn(acc4[t].z, acc4[t].w);
    }
  }
  __syncthreads();

  // level-0 composite
  for (int idx=tid; idx<4*784; idx+=256){
    int t = idx / 784, pix = idx - t*784;
    int r = pix / 28, c = pix - r*28;
    float s = 0.f;
    #pragma unroll
    for (int k=0;k<4;k++){
      const float* ap = av + (4 + t*4 + k)*4;
      s += bilinh(xh + (t*4+k)*784, ap[0], ap[1], ap[2], ap[3], r, c);
    }
    o0[t*784 + pix] = s;
  }
  __syncthreads();

  // level-1 composite -> d_out
  for (int idx=tid; idx<784; idx+=256){
    int r = idx / 28, c = idx - r*28;
    float s = 0.f;
    #pragma unroll
    for (int t=0;t<4;t++){
      const float* ap = av + t*4;
      s += bilin(o0 + t*784, ap[0], ap[1], ap[2], ap[3], r, c);
    }
    outp[(size_t)b*784 + idx] = s;
  }
}

extern "C" void kernel_launch(void* const* d_in, const int* in_sizes, int n_in,
                              void* d_out, int out_size, void* d_ws, size_t ws_size,
                              hipStream_t stream)
{
  const float* z   = (const float*)d_in[1];
  const float* sw1 = (const float*)d_in[2];
  const float* sb1 = (const float*)d_in[3];
  const float* sw2 = (const float*)d_in[4];
  const float* sb2 = (const float*)d_in[5];
  const float* sw3 = (const float*)d_in[6];
  const float* sb3 = (const float*)d_in[7];
  const float* pw1 = (const float*)d_in[8];
  const float* pb1 = (const float*)d_in[9];
  const float* pw2 = (const float*)d_in[10];
  const float* pb2 = (const float*)d_in[11];
  const float* pw3 = (const float*)d_in[12];
  const float* pb3 = (const float*)d_in[13];

  float* ws = (float*)d_ws;
  float*  Ps = ws;                                   // 1024*10464
  float*  Pp = ws + 10715136;                        // 1024*10596
  __half* Pd = (__half*)(ws + 21565440);             // 1024*25872 halves
  float*  Dm = ws + 34811904;                        // 16*1024*32
  float*  Am = ws + 35336192;                        // 20*1024*4
  unsigned short* h2s_hi = (unsigned short*)(ws + 35418112);   // 1024*64 each
  unsigned short* h2s_lo = h2s_hi + 65536;
  unsigned short* h2p_hi = h2s_hi + 131072;
  unsigned short* h2p_lo = h2s_hi + 196608;
  float* outp = (float*)d_out;

  (void)hipFuncSetAttribute(reinterpret_cast<const void*>(k_dec),
                            hipFuncAttributeMaxDynamicSharedMemorySize,
                            40064);

  hipLaunchKernelGGL(k_backbone, dim3(1024), dim3(128), 0, stream,
                     z, sw1,sb1,sw2,sb2, pw1,pb1,pw2,pb2,
                     h2s_hi, h2s_lo, h2p_hi, h2p_lo);
  hipLaunchKernelGGL(k_params5, dim3(330), dim3(256), 0, stream,
                     h2s_hi, h2s_lo, h2p_hi, h2p_lo,
                     sw3, sb3, pw3, pb3, Ps, Pp);
  hipLaunchKernelGGL(k_seq_pd, dim3(PD_TILES + 1024), dim3(256), 0, stream,
                     h2s_hi, h2s_lo, sw3, sb3, Pd, Ps, Pp, Dm, Am);
  hipLaunchKernelGGL(k_dec, dim3(1024), dim3(256), 40064, stream,
                     Pd, Dm, Am, outp);
}

// Round 12
// 146.102 us; speedup vs baseline: 1.3970x; 1.3970x over previous
//
#include <hip/hip_runtime.h>
#include <hip/hip_fp16.h>
#include <cmath>

#define BATCH 1024
#define SOUT 36336
#define POUT 10596
#define PS_COLS 10464   // s params compacted (dec2 block removed)
#define PP_COLS 10596
#define PD_COLS 25872   // s dec2 block (W 32x784 + b 784)

typedef __attribute__((ext_vector_type(8))) short bf16x8;
typedef __attribute__((ext_vector_type(4))) float f32x4;

__device__ __forceinline__ float sigmoidf_(float x){ return 1.0f/(1.0f+__expf(-x)); }
__device__ __forceinline__ float reluf_(float x){ return x>0.0f?x:0.0f; }

__device__ __forceinline__ void bf16split(float f, unsigned short& hi, unsigned short& lo){
  unsigned u = __float_as_uint(f);
  hi = (unsigned short)(u >> 16);
  float fhi = __uint_as_float(((unsigned)hi) << 16);
  float rem = f - fhi;                       // exact in fp32
  lo = (unsigned short)(__float_as_uint(rem) >> 16);
}

// ---------------- K1: backbone hidden h2 (s and p), emitted as bf16 hi/lo ---------
__global__ __launch_bounds__(128) void k_backbone(
    const float* __restrict__ z,
    const float* __restrict__ sw1, const float* __restrict__ sb1,
    const float* __restrict__ sw2, const float* __restrict__ sb2,
    const float* __restrict__ pw1, const float* __restrict__ pb1,
    const float* __restrict__ pw2, const float* __restrict__ pb2,
    unsigned short* __restrict__ h2s_hi, unsigned short* __restrict__ h2s_lo,
    unsigned short* __restrict__ h2p_hi, unsigned short* __restrict__ h2p_lo)
{
  __shared__ float zsh[32];
  __shared__ float h1sh[2][64];
  const int b = blockIdx.x;
  const int tid = threadIdx.x;
  const int g = tid >> 6, o = tid & 63;
  if (tid < 32) zsh[tid] = z[b*32 + tid];
  __syncthreads();
  const float* w1 = g ? pw1 : sw1;
  const float* b1 = g ? pb1 : sb1;
  float acc = b1[o];
  #pragma unroll
  for (int i=0;i<32;i++) acc += zsh[i]*w1[i*64+o];
  h1sh[g][o] = reluf_(acc);
  __syncthreads();
  const float* w2 = g ? pw2 : sw2;
  const float* b2 = g ? pb2 : sb2;
  float acc2 = b2[o];
  #pragma unroll
  for (int i=0;i<64;i++) acc2 += h1sh[g][i]*w2[i*64+o];
  float v = reluf_(acc2);
  unsigned short hi, lo;
  bf16split(v, hi, lo);
  (g ? h2p_hi : h2s_hi)[b*64+o] = hi;
  (g ? h2p_lo : h2s_lo)[b*64+o] = lo;
}

// ---------------- K2: all three params GEMMs on MFMA (bf16 hi/lo split) -----------
__global__ __launch_bounds__(256, 2) void k_params5(
    const unsigned short* __restrict__ h2s_hi, const unsigned short* __restrict__ h2s_lo,
    const unsigned short* __restrict__ h2p_hi, const unsigned short* __restrict__ h2p_lo,
    const float* __restrict__ sw3, const float* __restrict__ sb3,
    const float* __restrict__ pw3, const float* __restrict__ pb3,
    float* __restrict__ Ps, float* __restrict__ Pp, __half* __restrict__ Pd)
{
  __shared__ __align__(16) unsigned short wth[64][72];   // w3^T hi, padded
  __shared__ __align__(16) unsigned short wtl[64][72];   // w3^T lo
  int xt = blockIdx.x;
  const unsigned short *ahi, *alo;
  const float *w3, *b3;
  float* outF = nullptr; __half* outH = nullptr;
  int OC, thr, off, stride;
  if (xt < 164){
    ahi=h2s_hi; alo=h2s_lo; w3=sw3; b3=sb3; outF=Ps;
    OC=PS_COLS; thr=4192; off=25872; stride=SOUT;
  } else if (xt < 330){
    xt -= 164;
    ahi=h2p_hi; alo=h2p_lo; w3=pw3; b3=pb3; outF=Pp;
    OC=PP_COLS; thr=0x40000000; off=0; stride=POUT;
  } else {
    xt -= 330;
    ahi=h2s_hi; alo=h2s_lo; w3=sw3; b3=sb3; outH=Pd;
    OC=PD_COLS; thr=0; off=4192; stride=SOUT;
  }
  const int c0 = xt*64;
  const int tid = threadIdx.x;

  for (int idx=tid; idx<4096; idx+=256){
    int j = idx >> 6, cc = idx & 63;
    int c = c0 + cc; if (c > OC-1) c = OC-1;
    int src = (c < thr) ? c : c + off;
    float f = w3[(size_t)j*stride + src];
    unsigned short hi, lo;
    bf16split(f, hi, lo);
    wth[cc][j] = hi; wtl[cc][j] = lo;
  }
  __syncthreads();

  const int wv = tid >> 6, l = tid & 63;
  const int lr = l & 15, lq = l >> 4;

  bf16x8 Bh[2][4], Bl[2][4];
  #pragma unroll
  for (int ks=0; ks<2; ks++){
    #pragma unroll
    for (int ct=0; ct<4; ct++){
      const int row = ct*16 + lr;
      const int joff = ks*32 + lq*8;
      Bh[ks][ct] = *reinterpret_cast<const bf16x8*>(&wth[row][joff]);
      Bl[ks][ct] = *reinterpret_cast<const bf16x8*>(&wtl[row][joff]);
    }
  }
  float bv[4];
  #pragma unroll
  for (int ct=0; ct<4; ct++){
    int c = c0 + ct*16 + lr; if (c > OC-1) c = OC-1;
    int src = (c < thr) ? c : c + off;
    bv[ct] = b3[src];
  }

  for (int bsub=0; bsub<16; bsub++){
    const int arow = bsub*64 + wv*16 + lr;
    const unsigned short* ah = ahi + arow*64;
    const unsigned short* al = alo + arow*64;
    bf16x8 Ah0 = *reinterpret_cast<const bf16x8*>(ah + lq*8);
    bf16x8 Ah1 = *reinterpret_cast<const bf16x8*>(ah + 32 + lq*8);
    bf16x8 Al0 = *reinterpret_cast<const bf16x8*>(al + lq*8);
    bf16x8 Al1 = *reinterpret_cast<const bf16x8*>(al + 32 + lq*8);
    #pragma unroll
    for (int ct=0; ct<4; ct++){
      f32x4 acc = {0.f,0.f,0.f,0.f};
      acc = __builtin_amdgcn_mfma_f32_16x16x32_bf16(Ah0, Bh[0][ct], acc, 0,0,0);
      acc = __builtin_amdgcn_mfma_f32_16x16x32_bf16(Ah1, Bh[1][ct], acc, 0,0,0);
      acc = __builtin_amdgcn_mfma_f32_16x16x32_bf16(Ah0, Bl[0][ct], acc, 0,0,0);
      acc = __builtin_amdgcn_mfma_f32_16x16x32_bf16(Ah1, Bl[1][ct], acc, 0,0,0);
      acc = __builtin_amdgcn_mfma_f32_16x16x32_bf16(Al0, Bh[0][ct], acc, 0,0,0);
      acc = __builtin_amdgcn_mfma_f32_16x16x32_bf16(Al1, Bh[1][ct], acc, 0,0,0);
      const int c = c0 + ct*16 + lr;
      if (c < OC){
        const int r0 = bsub*64 + wv*16 + lq*4;
        const float bb = bv[ct];
        if (outF){
          outF[(size_t)(r0+0)*OC + c] = acc[0] + bb;
          outF[(size_t)(r0+1)*OC + c] = acc[1] + bb;
          outF[(size_t)(r0+2)*OC + c] = acc[2] + bb;
          outF[(size_t)(r0+3)*OC + c] = acc[3] + bb;
        } else {
          outH[(size_t)(r0+0)*OC + c] = __float2half(acc[0] + bb);
          outH[(size_t)(r0+1)*OC + c] = __float2half(acc[1] + bb);
          outH[(size_t)(r0+2)*OC + c] = __float2half(acc[2] + bb);
          outH[(size_t)(r0+3)*OC + c] = __float2half(acc[3] + bb);
        }
      }
    }
  }
}

// ---------------- K3: hyper-GRU seq, wave-per-net (1 barrier/substep) ----------
// Block = 128 threads = 1 batch elem: wave0 = s-net, wave1 = p-net.
// All intra-substep deps are intra-wave (compiler lgkmcnt ordering, no barrier).
// Only the xv=[s_h|p_h] handoff crosses waves -> single __syncthreads per substep.
// Per-lane registers: up to 6x32 weight floats (~220 VGPR); cap 256 via (128,2).
__global__ __launch_bounds__(128, 2) void k_seq2(
    const float* __restrict__ Ps, const float* __restrict__ Pp,
    float* __restrict__ Dout, float* __restrict__ Aout)
{
  __shared__ float xvT[64], xvI[64], initZ[64], hst[64];
  __shared__ float psA[128], e2s[64], rhs[64], d1s[32], d2w[132];

  const int b = blockIdx.x;
  const int tid = threadIdx.x;
  const int g = tid >> 6, l = tid & 63;
  const int o = l & 31, h = l >> 5;
  const float* Gp = g ? (Pp + (size_t)b*PP_COLS) : (Ps + (size_t)b*PS_COLS);
  const int rnn = g ? 4324 : 4192;

  float wE1[32];            // all lanes: enc1 col o, K-half h
  float wED[32];            // l<32: enc2 col o ; l>=32: dec1 col o
  float wK[32];             // all: gru-k col l (of 96)
  float wR[32];             // all: gru-rk col l
  float wK2[32], wR2[32];   // l<32: gru-k / gru-rk col 64+o
  float bE1=0.f, bED=0.f, bK=0.f, bK2=0.f;

  #pragma unroll
  for (int i=0;i<32;i++) wE1[i] = Gp[h*1024 + i*32 + o];
  #pragma unroll
  for (int i=0;i<32;i++) wK[i]  = Gp[rnn + i*96 + l];
  #pragma unroll
  for (int i=0;i<32;i++) wR[i]  = Gp[rnn + 3072 + i*96 + l];
  bK = Gp[rnn + 6144 + l];
  if (l < 32){
    #pragma unroll
    for (int i=0;i<32;i++) wED[i] = Gp[2080 + i*32 + o];
    #pragma unroll
    for (int i=0;i<32;i++) wK2[i] = Gp[rnn + i*96 + 64 + o];
    #pragma unroll
    for (int i=0;i<32;i++) wR2[i] = Gp[rnn + 3072 + i*96 + 64 + o];
    bE1 = Gp[2048 + o];
    bED = Gp[3104 + o];                 // e2 bias
    bK2 = Gp[rnn + 6144 + 64 + o];
  } else {
    #pragma unroll
    for (int i=0;i<32;i++) wED[i] = Gp[3136 + i*32 + o];
    bED = Gp[4160 + o];                 // dec1 bias
  }
  if (g == 1){                          // p dec2 weights -> LDS (tiny)
    for (int idx=l; idx<132; idx+=64) d2w[idx] = Gp[4192 + idx];
  }

  if (tid < 64) hst[tid] = 0.f;
  if (tid < 32) initZ[tid] = Ps[(size_t)b*PS_COLS + 10432 + tid];
  else if (tid < 64) initZ[tid] = Pp[(size_t)b*PP_COLS + 10564 + (tid-32)];
  __syncthreads();
  if (tid < 64) xvT[tid] = initZ[tid];
  __syncthreads();

  auto substep = [&](const float* xv, int aidx, int t16, bool isTop){
    // 1: e1 K-half psums (all lanes)
    {
      float a0 = (l < 32) ? bE1 : 0.f, a1=0.f, a2=0.f, a3=0.f;
      const float4* x4 = reinterpret_cast<const float4*>(&xv[h*32]);
      #pragma unroll
      for (int i=0;i<8;i++){
        float4 v = x4[i];
        a0 += v.x*wE1[4*i+0]; a1 += v.y*wE1[4*i+1];
        a2 += v.z*wE1[4*i+2]; a3 += v.w*wE1[4*i+3];
      }
      psA[g*64 + h*32 + o] = (a0+a1)+(a2+a3);
    }
    // 2: e2 (lanes 0-31) — psA same-wave, lgkm-ordered
    if (l < 32){
      float a0=bED, a1=0.f, a2=0.f, a3=0.f;
      const float4* p0 = reinterpret_cast<const float4*>(&psA[g*64]);
      const float4* p1 = reinterpret_cast<const float4*>(&psA[g*64+32]);
      #pragma unroll
      for (int i=0;i<8;i++){
        float4 u = p0[i], v = p1[i];
        a0 += reluf_(u.x+v.x)*wED[4*i+0];
        a1 += reluf_(u.y+v.y)*wED[4*i+1];
        a2 += reluf_(u.z+v.z)*wED[4*i+2];
        a3 += reluf_(u.w+v.w)*wED[4*i+3];
      }
      e2s[g*32 + o] = (a0+a1)+(a2+a3);
    }
    // 3: gxh = gx[l]+gh[l] (all lanes); xh col 64+o (lanes 0-31)
    float gxh, xh = 0.f;
    {
      float a0=bK, a1=0.f, r0=0.f, r1=0.f, x0=bK2, x1=0.f;
      const float4* e4 = reinterpret_cast<const float4*>(&e2s[g*32]);
      const float4* h4 = reinterpret_cast<const float4*>(&hst[g*32]);
      #pragma unroll
      for (int i=0;i<8;i++){
        float4 u = e4[i], v = h4[i];
        a0 += u.x*wK[4*i+0] + u.z*wK[4*i+2];
        a1 += u.y*wK[4*i+1] + u.w*wK[4*i+3];
        r0 += v.x*wR[4*i+0] + v.z*wR[4*i+2];
        r1 += v.y*wR[4*i+1] + v.w*wR[4*i+3];
        if (l < 32){
          x0 += u.x*wK2[4*i+0] + u.z*wK2[4*i+2];
          x1 += u.y*wK2[4*i+1] + u.w*wK2[4*i+3];
        }
      }
      gxh = (a0+a1)+(r0+r1);
      xh  = x0+x1;
    }
    // 4: r-gate (lanes 32-63 FIRST — producers before consumers in wave order)
    if (l >= 32){
      float rg = sigmoidf_(gxh);
      rhs[g*32 + o] = rg * hst[g*32 + o];
    }
    // 5: z-gate + candidate + h-update (lanes 0-31)
    if (l < 32){
      float zg = sigmoidf_(gxh);
      float a0=0.f, a1=0.f, a2=0.f, a3=0.f;
      const float4* r4 = reinterpret_cast<const float4*>(&rhs[g*32]);
      #pragma unroll
      for (int i=0;i<8;i++){
        float4 v = r4[i];
        a0 += v.x*wR2[4*i+0]; a1 += v.y*wR2[4*i+1];
        a2 += v.z*wR2[4*i+2]; a3 += v.w*wR2[4*i+3];
      }
      float hh = tanhf(xh + (a0+a1)+(a2+a3));
      float ho = hst[g*32+o];
      float hn = zg*ho + (1.f-zg)*hh;
      hst[g*32+o] = hn;
      if (isTop){ xvT[g*32+o] = hn; xvI[g*32+o] = initZ[g*32+o]; }
      else        xvI[g*32+o] = hn;
    }
    // 6: dec1 (lanes 32-63) on NEW h — same-wave ordering
    if (l >= 32 && (g==1 || t16 >= 0)){
      float a0=bED, a1=0.f, a2=0.f, a3=0.f;
      const float4* h4 = reinterpret_cast<const float4*>(&hst[g*32]);
      #pragma unroll
      for (int i=0;i<8;i++){
        float4 v = h4[i];
        a0 += v.x*wED[4*i+0]; a1 += v.y*wED[4*i+1];
        a2 += v.z*wED[4*i+2]; a3 += v.w*wED[4*i+3];
      }
      float d = reluf_((a0+a1)+(a2+a3));
      if (g == 0) Dout[((size_t)t16*BATCH + b)*32 + o] = d;
      else d1s[o] = d;
    }
    // 7: p dec2 -> a (wave1 lanes 32-35), weights from LDS
    if (g == 1 && l >= 32 && l < 36){
      const int c = l - 32;
      float acc = d2w[128 + c];
      #pragma unroll
      for (int i=0;i<32;i++) acc += d1s[i]*d2w[i*4 + c];
      Aout[((size_t)aidx*BATCH + b)*4 + c] = acc;
    }
    __syncthreads();   // xvT/xvI visible to the other wave
  };

  for (int t=0;t<4;t++){
    substep(xvT, t, -1, true);
    for (int k=0;k<4;k++){
      substep(xvI, 4 + t*4 + k, t*4 + k, false);
    }
  }
}

// ---------------- bilinear samplers (fp32 and fp16 LDS images) ----------------
__device__ __forceinline__ float fetchpix(const float* __restrict__ img, int y, int x){
  if ((unsigned)y >= 28u || (unsigned)x >= 28u) return 0.0f;
  return img[y*28 + x];
}
__device__ __forceinline__ float fetchpixh(const __half* __restrict__ img, int y, int x){
  if ((unsigned)y >= 28u || (unsigned)x >= 28u) return 0.0f;
  return __half2float(img[y*28 + x]);
}
#define BILIN_BODY(FETCH) \
  const float stepv = 2.0f/27.0f; \
  float gxv = -1.0f + stepv*(float)c; \
  float gyv = -1.0f + stepv*(float)r; \
  float srcx = (a0 + 1.0f)*gxv + a2; \
  float srcy = (a1 + 1.0f)*gyv + a3; \
  float px = (srcx + 1.0f)*13.5f; \
  float py = (srcy + 1.0f)*13.5f; \
  float x0f = floorf(px), y0f = floorf(py); \
  float wx = px - x0f, wy = py - y0f; \
  int x0 = (int)x0f, y0 = (int)y0f; \
  float v00 = FETCH(img, y0,   x0); \
  float v01 = FETCH(img, y0,   x0+1); \
  float v10 = FETCH(img, y0+1, x0); \
  float v11 = FETCH(img, y0+1, x0+1); \
  return v00*(1.0f-wx)*(1.0f-wy) + v01*wx*(1.0f-wy) \
       + v10*(1.0f-wx)*wy + v11*wx*wy;

__device__ __forceinline__ float bilin(const float* __restrict__ img,
    float a0, float a1, float a2, float a3, int r, int c){ BILIN_BODY(fetchpix) }
__device__ __forceinline__ float bilinh(const __half* __restrict__ img,
    float a0, float a1, float a2, float a3, int r, int c){ BILIN_BODY(fetchpixh) }

// ---------------- K4: fused decode: xhat (fp16 Pd stream) + both composites --------
__global__ __launch_bounds__(256, 4) void k_dec(
    const __half* __restrict__ Pd, const float* __restrict__ Dm,
    const float* __restrict__ Am, float* __restrict__ outp)
{
  extern __shared__ float lds[];
  float*  o0 = lds;                                      // 3136 f32
  float*  Da = lds + 3136;                               // 528
  float*  av = lds + 3664;                               // 80
  __half* xh = reinterpret_cast<__half*>(lds + 3744);    // 16*784 halves (25088 B)
  const int b = blockIdx.x;
  const int tid = threadIdx.x;

  for (int idx=tid; idx<512; idx+=256){
    int t = idx >> 5, i = idx & 31;
    Da[t*33 + i] = Dm[((size_t)t*BATCH + b)*32 + i];
  }
  if (tid < 16) Da[tid*33 + 32] = 1.0f;
  if (tid < 80) av[tid] = Am[((size_t)(tid>>2)*BATCH + b)*4 + (tid&3)];

  float4 acc4[16];
  #pragma unroll
  for (int t=0;t<16;t++) acc4[t] = make_float4(0.f,0.f,0.f,0.f);
  __syncthreads();

  const __half* Pdb = Pd + (size_t)b*PD_COLS;
  #pragma unroll 3
  for (int i=0;i<33;i++){
    const __half* row = Pdb + (i<32 ? i*784 : 25088);
    float4 v = make_float4(0.f,0.f,0.f,0.f);
    if (tid < 196){
      const __half2 h0 = reinterpret_cast<const __half2*>(row)[tid*2];
      const __half2 h1 = reinterpret_cast<const __half2*>(row)[tid*2+1];
      float2 f0 = __half22float2(h0), f1 = __half22float2(h1);
      v = make_float4(f0.x, f0.y, f1.x, f1.y);
    }
    #pragma unroll
    for (int t=0;t<16;t++){
      float da = Da[t*33 + i];
      acc4[t].x += da*v.x; acc4[t].y += da*v.y;
      acc4[t].z += da*v.z; acc4[t].w += da*v.w;
    }
  }
  if (tid < 196){
    #pragma unroll
    for (int t=0;t<16;t++){
      __half2* dst = reinterpret_cast<__half2*>(xh + t*784 + tid*4);
      dst[0] = __floats2half2_rn(acc4[t].x, acc4[t].y);
      dst[1] = __floats2half2_rn(acc4[t].z, acc4[t].w);
    }
  }
  __syncthreads();

  // level-0 composite
  for (int idx=tid; idx<4*784; idx+=256){
    int t = idx / 784, pix = idx - t*784;
    int r = pix / 28, c = pix - r*28;
    float s = 0.f;
    #pragma unroll
    for (int k=0;k<4;k++){
      const float* ap = av + (4 + t*4 + k)*4;
      s += bilinh(xh + (t*4+k)*784, ap[0], ap[1], ap[2], ap[3], r, c);
    }
    o0[t*784 + pix] = s;
  }
  __syncthreads();

  // level-1 composite -> d_out
  for (int idx=tid; idx<784; idx+=256){
    int r = idx / 28, c = idx - r*28;
    float s = 0.f;
    #pragma unroll
    for (int t=0;t<4;t++){
      const float* ap = av + t*4;
      s += bilin(o0 + t*784, ap[0], ap[1], ap[2], ap[3], r, c);
    }
    outp[(size_t)b*784 + idx] = s;
  }
}

extern "C" void kernel_launch(void* const* d_in, const int* in_sizes, int n_in,
                              void* d_out, int out_size, void* d_ws, size_t ws_size,
                              hipStream_t stream)
{
  const float* z   = (const float*)d_in[1];
  const float* sw1 = (const float*)d_in[2];
  const float* sb1 = (const float*)d_in[3];
  const float* sw2 = (const float*)d_in[4];
  const float* sb2 = (const float*)d_in[5];
  const float* sw3 = (const float*)d_in[6];
  const float* sb3 = (const float*)d_in[7];
  const float* pw1 = (const float*)d_in[8];
  const float* pb1 = (const float*)d_in[9];
  const float* pw2 = (const float*)d_in[10];
  const float* pb2 = (const float*)d_in[11];
  const float* pw3 = (const float*)d_in[12];
  const float* pb3 = (const float*)d_in[13];

  float* ws = (float*)d_ws;
  float*  Ps = ws;                                   // 1024*10464
  float*  Pp = ws + 10715136;                        // 1024*10596
  __half* Pd = (__half*)(ws + 21565440);             // 1024*25872 halves
  float*  Dm = ws + 34811904;                        // 16*1024*32
  float*  Am = ws + 35336192;                        // 20*1024*4
  unsigned short* h2s_hi = (unsigned short*)(ws + 35418112);   // 1024*64 each
  unsigned short* h2s_lo = h2s_hi + 65536;
  unsigned short* h2p_hi = h2s_hi + 131072;
  unsigned short* h2p_lo = h2s_hi + 196608;
  float* outp = (float*)d_out;

  (void)hipFuncSetAttribute(reinterpret_cast<const void*>(k_dec),
                            hipFuncAttributeMaxDynamicSharedMemorySize,
                            40064);

  hipLaunchKernelGGL(k_backbone, dim3(1024), dim3(128), 0, stream,
                     z, sw1,sb1,sw2,sb2, pw1,pb1,pw2,pb2,
                     h2s_hi, h2s_lo, h2p_hi, h2p_lo);
  hipLaunchKernelGGL(k_params5, dim3(735), dim3(256), 0, stream,
                     h2s_hi, h2s_lo, h2p_hi, h2p_lo,
                     sw3, sb3, pw3, pb3, Ps, Pp, Pd);
  hipLaunchKernelGGL(k_seq2, dim3(1024), dim3(128), 0, stream,
                     Ps, Pp, Dm, Am);
  hipLaunchKernelGGL(k_dec, dim3(1024), dim3(256), 40064, stream,
                     Pd, Dm, Am, outp);
}

// Round 13
// 137.153 us; speedup vs baseline: 1.4881x; 1.0652x over previous
//
#include <hip/hip_runtime.h>
#include <hip/hip_fp16.h>
#include <cmath>

#define BATCH 1024
#define SOUT 36336
#define POUT 10596
#define PS_COLS 10464   // s params compacted (dec2 block removed)
#define PP_COLS 10596
#define PD_COLS 25872   // s dec2 block (W 32x784 + b 784)

typedef __attribute__((ext_vector_type(8))) short bf16x8;
typedef __attribute__((ext_vector_type(4))) float f32x4;
typedef __attribute__((ext_vector_type(2))) float f32x2;

__device__ __forceinline__ float sigmoidf_(float x){ return 1.0f/(1.0f+__expf(-x)); }
__device__ __forceinline__ float reluf_(float x){ return x>0.0f?x:0.0f; }
__device__ __forceinline__ float fast_tanhf(float x){
  float e = __expf(2.f*x);
  return 1.f - 2.f/(e + 1.f);
}

__device__ __forceinline__ void bf16split(float f, unsigned short& hi, unsigned short& lo){
  unsigned u = __float_as_uint(f);
  hi = (unsigned short)(u >> 16);
  float fhi = __uint_as_float(((unsigned)hi) << 16);
  float rem = f - fhi;                       // exact in fp32
  lo = (unsigned short)(__float_as_uint(rem) >> 16);
}

// ---------------- K1: backbone hidden h2 (s and p), emitted as bf16 hi/lo ---------
__global__ __launch_bounds__(128) void k_backbone(
    const float* __restrict__ z,
    const float* __restrict__ sw1, const float* __restrict__ sb1,
    const float* __restrict__ sw2, const float* __restrict__ sb2,
    const float* __restrict__ pw1, const float* __restrict__ pb1,
    const float* __restrict__ pw2, const float* __restrict__ pb2,
    unsigned short* __restrict__ h2s_hi, unsigned short* __restrict__ h2s_lo,
    unsigned short* __restrict__ h2p_hi, unsigned short* __restrict__ h2p_lo)
{
  __shared__ float zsh[32];
  __shared__ float h1sh[2][64];
  const int b = blockIdx.x;
  const int tid = threadIdx.x;
  const int g = tid >> 6, o = tid & 63;
  if (tid < 32) zsh[tid] = z[b*32 + tid];
  __syncthreads();
  const float* w1 = g ? pw1 : sw1;
  const float* b1 = g ? pb1 : sb1;
  float acc = b1[o];
  #pragma unroll
  for (int i=0;i<32;i++) acc += zsh[i]*w1[i*64+o];
  h1sh[g][o] = reluf_(acc);
  __syncthreads();
  const float* w2 = g ? pw2 : sw2;
  const float* b2 = g ? pb2 : sb2;
  float acc2 = b2[o];
  #pragma unroll
  for (int i=0;i<64;i++) acc2 += h1sh[g][i]*w2[i*64+o];
  float v = reluf_(acc2);
  unsigned short hi, lo;
  bf16split(v, hi, lo);
  (g ? h2p_hi : h2s_hi)[b*64+o] = hi;
  (g ? h2p_lo : h2s_lo)[b*64+o] = lo;
}

// ---------------- K2: all three params GEMMs on MFMA (bf16 hi/lo split) -----------
__global__ __launch_bounds__(256, 2) void k_params5(
    const unsigned short* __restrict__ h2s_hi, const unsigned short* __restrict__ h2s_lo,
    const unsigned short* __restrict__ h2p_hi, const unsigned short* __restrict__ h2p_lo,
    const float* __restrict__ sw3, const float* __restrict__ sb3,
    const float* __restrict__ pw3, const float* __restrict__ pb3,
    float* __restrict__ Ps, float* __restrict__ Pp, __half* __restrict__ Pd)
{
  __shared__ __align__(16) unsigned short wth[64][72];   // w3^T hi, padded
  __shared__ __align__(16) unsigned short wtl[64][72];   // w3^T lo
  int xt = blockIdx.x;
  const unsigned short *ahi, *alo;
  const float *w3, *b3;
  float* outF = nullptr; __half* outH = nullptr;
  int OC, thr, off, stride;
  if (xt < 164){
    ahi=h2s_hi; alo=h2s_lo; w3=sw3; b3=sb3; outF=Ps;
    OC=PS_COLS; thr=4192; off=25872; stride=SOUT;
  } else if (xt < 330){
    xt -= 164;
    ahi=h2p_hi; alo=h2p_lo; w3=pw3; b3=pb3; outF=Pp;
    OC=PP_COLS; thr=0x40000000; off=0; stride=POUT;
  } else {
    xt -= 330;
    ahi=h2s_hi; alo=h2s_lo; w3=sw3; b3=sb3; outH=Pd;
    OC=PD_COLS; thr=0; off=4192; stride=SOUT;
  }
  const int c0 = xt*64;
  const int tid = threadIdx.x;

  for (int idx=tid; idx<4096; idx+=256){
    int j = idx >> 6, cc = idx & 63;
    int c = c0 + cc; if (c > OC-1) c = OC-1;
    int src = (c < thr) ? c : c + off;
    float f = w3[(size_t)j*stride + src];
    unsigned short hi, lo;
    bf16split(f, hi, lo);
    wth[cc][j] = hi; wtl[cc][j] = lo;
  }
  __syncthreads();

  const int wv = tid >> 6, l = tid & 63;
  const int lr = l & 15, lq = l >> 4;

  bf16x8 Bh[2][4], Bl[2][4];
  #pragma unroll
  for (int ks=0; ks<2; ks++){
    #pragma unroll
    for (int ct=0; ct<4; ct++){
      const int row = ct*16 + lr;
      const int joff = ks*32 + lq*8;
      Bh[ks][ct] = *reinterpret_cast<const bf16x8*>(&wth[row][joff]);
      Bl[ks][ct] = *reinterpret_cast<const bf16x8*>(&wtl[row][joff]);
    }
  }
  float bv[4];
  #pragma unroll
  for (int ct=0; ct<4; ct++){
    int c = c0 + ct*16 + lr; if (c > OC-1) c = OC-1;
    int src = (c < thr) ? c : c + off;
    bv[ct] = b3[src];
  }

  for (int bsub=0; bsub<16; bsub++){
    const int arow = bsub*64 + wv*16 + lr;
    const unsigned short* ah = ahi + arow*64;
    const unsigned short* al = alo + arow*64;
    bf16x8 Ah0 = *reinterpret_cast<const bf16x8*>(ah + lq*8);
    bf16x8 Ah1 = *reinterpret_cast<const bf16x8*>(ah + 32 + lq*8);
    bf16x8 Al0 = *reinterpret_cast<const bf16x8*>(al + lq*8);
    bf16x8 Al1 = *reinterpret_cast<const bf16x8*>(al + 32 + lq*8);
    #pragma unroll
    for (int ct=0; ct<4; ct++){
      f32x4 acc = {0.f,0.f,0.f,0.f};
      acc = __builtin_amdgcn_mfma_f32_16x16x32_bf16(Ah0, Bh[0][ct], acc, 0,0,0);
      acc = __builtin_amdgcn_mfma_f32_16x16x32_bf16(Ah1, Bh[1][ct], acc, 0,0,0);
      acc = __builtin_amdgcn_mfma_f32_16x16x32_bf16(Ah0, Bl[0][ct], acc, 0,0,0);
      acc = __builtin_amdgcn_mfma_f32_16x16x32_bf16(Ah1, Bl[1][ct], acc, 0,0,0);
      acc = __builtin_amdgcn_mfma_f32_16x16x32_bf16(Al0, Bh[0][ct], acc, 0,0,0);
      acc = __builtin_amdgcn_mfma_f32_16x16x32_bf16(Al1, Bh[1][ct], acc, 0,0,0);
      const int c = c0 + ct*16 + lr;
      if (c < OC){
        const int r0 = bsub*64 + wv*16 + lq*4;
        const float bb = bv[ct];
        if (outF){
          outF[(size_t)(r0+0)*OC + c] = acc[0] + bb;
          outF[(size_t)(r0+1)*OC + c] = acc[1] + bb;
          outF[(size_t)(r0+2)*OC + c] = acc[2] + bb;
          outF[(size_t)(r0+3)*OC + c] = acc[3] + bb;
        } else {
          outH[(size_t)(r0+0)*OC + c] = __float2half(acc[0] + bb);
          outH[(size_t)(r0+1)*OC + c] = __float2half(acc[1] + bb);
          outH[(size_t)(r0+2)*OC + c] = __float2half(acc[2] + bb);
          outH[(size_t)(r0+3)*OC + c] = __float2half(acc[3] + bb);
        }
      }
    }
  }
}

// ---------------- K3: hyper-GRU seq, wave-per-net, register-resident weights ------
// waves_per_eu(2,2): exactly the occupancy we need (2048 waves = 2/SIMD) and a
// 256-VGPR budget so the ~160-float weight set stays in registers (no remat).
// wX packing: lanes <32 hold wR2 (candidate), lanes >=32 hold wK2 (xh).
__global__ __launch_bounds__(128)
__attribute__((amdgpu_waves_per_eu(2, 2)))
void k_seq2(
    const float* __restrict__ Ps, const float* __restrict__ Pp,
    float* __restrict__ Dout, float* __restrict__ Aout)
{
  __shared__ float xvT[64], xvI[64], initZ[64], hst[64];
  __shared__ float psA[128], e2s[64], rhs[64], xhs[64], d1s[32], d2w[132];

  const int b = blockIdx.x;
  const int tid = threadIdx.x;
  const int g = tid >> 6, l = tid & 63;
  const int o = l & 31, h = l >> 5;
  const float* Gp = g ? (Pp + (size_t)b*PP_COLS) : (Ps + (size_t)b*PS_COLS);
  const int rnn = g ? 4324 : 4192;

  f32x2 wE1[16], wED[16], wK[16], wR[16], wX[16];
  float bE1, bED, bK, bK2;

  bE1 = Gp[2048 + o];
  bK  = Gp[rnn + 6144 + l];
  bK2 = Gp[rnn + 6144 + 64 + o];
  const int xb = (l < 32) ? (rnn + 3072) : rnn;   // wR2 : wK2
  #pragma unroll
  for (int i=0;i<16;i++){
    wE1[i].x = Gp[h*1024 + (2*i)*32 + o];   wE1[i].y = Gp[h*1024 + (2*i+1)*32 + o];
    wK[i].x  = Gp[rnn + (2*i)*96 + l];      wK[i].y  = Gp[rnn + (2*i+1)*96 + l];
    wR[i].x  = Gp[rnn + 3072 + (2*i)*96 + l];
    wR[i].y  = Gp[rnn + 3072 + (2*i+1)*96 + l];
    wX[i].x  = Gp[xb + (2*i)*96 + 64 + o];  wX[i].y  = Gp[xb + (2*i+1)*96 + 64 + o];
  }
  if (l < 32){
    #pragma unroll
    for (int i=0;i<16;i++){
      wED[i].x = Gp[2080 + (2*i)*32 + o];  wED[i].y = Gp[2080 + (2*i+1)*32 + o];
    }
    bED = Gp[3104 + o];
  } else {
    #pragma unroll
    for (int i=0;i<16;i++){
      wED[i].x = Gp[3136 + (2*i)*32 + o];  wED[i].y = Gp[3136 + (2*i+1)*32 + o];
    }
    bED = Gp[4160 + o];
  }
  if (g == 1){                          // p dec2 weights -> LDS (tiny)
    for (int idx=l; idx<132; idx+=64) d2w[idx] = Gp[4192 + idx];
  }

  if (tid < 64) hst[tid] = 0.f;
  if (tid < 32) initZ[tid] = Ps[(size_t)b*PS_COLS + 10432 + tid];
  else if (tid < 64) initZ[tid] = Pp[(size_t)b*PP_COLS + 10564 + (tid-32)];
  __syncthreads();
  if (tid < 64) xvT[tid] = initZ[tid];
  __syncthreads();

  auto substep = [&](const float* xv, int aidx, int t16, bool isTop){
    // 1: e1 K-half psums (all lanes)
    {
      f32x2 s0 = {0.f,0.f}, s1 = {0.f,0.f};
      const float4* x4 = reinterpret_cast<const float4*>(&xv[h*32]);
      #pragma unroll
      for (int i=0;i<8;i++){
        float4 v = x4[i];
        f32x2 vlo; vlo.x=v.x; vlo.y=v.y;
        f32x2 vhi; vhi.x=v.z; vhi.y=v.w;
        s0 += vlo*wE1[2*i];
        s1 += vhi*wE1[2*i+1];
      }
      psA[g*64 + l] = (s0.x+s0.y)+(s1.x+s1.y) + ((l<32)?bE1:0.f);
    }
    // 2: e2 = relu(e1) @ Wenc2 + b (lanes 0-31) — psA same-wave, lgkm-ordered
    if (l < 32){
      f32x2 s0 = {0.f,0.f}, s1 = {0.f,0.f};
      const float4* p0 = reinterpret_cast<const float4*>(&psA[g*64]);
      const float4* p1 = reinterpret_cast<const float4*>(&psA[g*64+32]);
      #pragma unroll
      for (int i=0;i<8;i++){
        float4 u = p0[i], v = p1[i];
        f32x2 elo; elo.x=reluf_(u.x+v.x); elo.y=reluf_(u.y+v.y);
        f32x2 ehi; ehi.x=reluf_(u.z+v.z); ehi.y=reluf_(u.w+v.w);
        s0 += elo*wED[2*i];
        s1 += ehi*wED[2*i+1];
      }
      e2s[g*32 + o] = (s0.x+s0.y)+(s1.x+s1.y) + bED;
    }
    // 3: gxh (all lanes); xh col 64+o + r-gate (lanes 32-63)
    float gxh;
    {
      f32x2 k0={0.f,0.f},k1={0.f,0.f},r0={0.f,0.f},r1={0.f,0.f},x0={0.f,0.f},x1={0.f,0.f};
      const float4* e4 = reinterpret_cast<const float4*>(&e2s[g*32]);
      const float4* h4 = reinterpret_cast<const float4*>(&hst[g*32]);
      #pragma unroll
      for (int i=0;i<8;i++){
        float4 u = e4[i], v = h4[i];
        f32x2 ulo; ulo.x=u.x; ulo.y=u.y;
        f32x2 uhi; uhi.x=u.z; uhi.y=u.w;
        f32x2 vlo; vlo.x=v.x; vlo.y=v.y;
        f32x2 vhi; vhi.x=v.z; vhi.y=v.w;
        k0 += ulo*wK[2*i]; k1 += uhi*wK[2*i+1];
        r0 += vlo*wR[2*i]; r1 += vhi*wR[2*i+1];
        x0 += ulo*wX[2*i]; x1 += uhi*wX[2*i+1];   // wX=wK2 on l>=32 (valid there)
      }
      gxh = (k0.x+k0.y)+(k1.x+k1.y) + bK + (r0.x+r0.y)+(r1.x+r1.y);
      if (l >= 32){
        xhs[g*32 + o] = (x0.x+x0.y)+(x1.x+x1.y) + bK2;
        float rg = sigmoidf_(gxh);
        rhs[g*32 + o] = rg * hst[g*32 + o];
      }
    }
    // 5: z-gate + candidate + h-update (lanes 0-31); wX=wR2 here
    if (l < 32){
      float zg = sigmoidf_(gxh);
      f32x2 s0 = {0.f,0.f}, s1 = {0.f,0.f};
      const float4* r4 = reinterpret_cast<const float4*>(&rhs[g*32]);
      #pragma unroll
      for (int i=0;i<8;i++){
        float4 v = r4[i];
        f32x2 vlo; vlo.x=v.x; vlo.y=v.y;
        f32x2 vhi; vhi.x=v.z; vhi.y=v.w;
        s0 += vlo*wX[2*i];
        s1 += vhi*wX[2*i+1];
      }
      float hh = fast_tanhf(xhs[g*32+o] + (s0.x+s0.y)+(s1.x+s1.y));
      float ho = hst[g*32+o];
      float hn = zg*ho + (1.f-zg)*hh;
      hst[g*32+o] = hn;
      if (isTop){ xvT[g*32+o] = hn; xvI[g*32+o] = initZ[g*32+o]; }
      else        xvI[g*32+o] = hn;
    }
    // 6: dec1 (lanes 32-63) on NEW h — same-wave ordering
    if (l >= 32 && (g==1 || t16 >= 0)){
      f32x2 s0 = {0.f,0.f}, s1 = {0.f,0.f};
      const float4* h4 = reinterpret_cast<const float4*>(&hst[g*32]);
      #pragma unroll
      for (int i=0;i<8;i++){
        float4 v = h4[i];
        f32x2 vlo; vlo.x=v.x; vlo.y=v.y;
        f32x2 vhi; vhi.x=v.z; vhi.y=v.w;
        s0 += vlo*wED[2*i];
        s1 += vhi*wED[2*i+1];
      }
      float d = reluf_((s0.x+s0.y)+(s1.x+s1.y) + bED);
      if (g == 0) Dout[((size_t)t16*BATCH + b)*32 + o] = d;
      else d1s[o] = d;
    }
    // 7: p dec2 -> a (wave1 lanes 32-35), weights from LDS
    if (g == 1 && l >= 32 && l < 36){
      const int c = l - 32;
      float acc = d2w[128 + c];
      #pragma unroll
      for (int i=0;i<32;i++) acc += d1s[i]*d2w[i*4 + c];
      Aout[((size_t)aidx*BATCH + b)*4 + c] = acc;
    }
    __syncthreads();   // xvT/xvI visible to the other wave
  };

  for (int t=0;t<4;t++){
    substep(xvT, t, -1, true);
    for (int k=0;k<4;k++){
      substep(xvI, 4 + t*4 + k, t*4 + k, false);
    }
  }
}

// ---------------- bilinear samplers (fp32 and fp16 LDS images) ----------------
__device__ __forceinline__ float fetchpix(const float* __restrict__ img, int y, int x){
  if ((unsigned)y >= 28u || (unsigned)x >= 28u) return 0.0f;
  return img[y*28 + x];
}
__device__ __forceinline__ float fetchpixh(const __half* __restrict__ img, int y, int x){
  if ((unsigned)y >= 28u || (unsigned)x >= 28u) return 0.0f;
  return __half2float(img[y*28 + x]);
}
#define BILIN_BODY(FETCH) \
  const float stepv = 2.0f/27.0f; \
  float gxv = -1.0f + stepv*(float)c; \
  float gyv = -1.0f + stepv*(float)r; \
  float srcx = (a0 + 1.0f)*gxv + a2; \
  float srcy = (a1 + 1.0f)*gyv + a3; \
  float px = (srcx + 1.0f)*13.5f; \
  float py = (srcy + 1.0f)*13.5f; \
  float x0f = floorf(px), y0f = floorf(py); \
  float wx = px - x0f, wy = py - y0f; \
  int x0 = (int)x0f, y0 = (int)y0f; \
  float v00 = FETCH(img, y0,   x0); \
  float v01 = FETCH(img, y0,   x0+1); \
  float v10 = FETCH(img, y0+1, x0); \
  float v11 = FETCH(img, y0+1, x0+1); \
  return v00*(1.0f-wx)*(1.0f-wy) + v01*wx*(1.0f-wy) \
       + v10*(1.0f-wx)*wy + v11*wx*wy;

__device__ __forceinline__ float bilin(const float* __restrict__ img,
    float a0, float a1, float a2, float a3, int r, int c){ BILIN_BODY(fetchpix) }
__device__ __forceinline__ float bilinh(const __half* __restrict__ img,
    float a0, float a1, float a2, float a3, int r, int c){ BILIN_BODY(fetchpixh) }

// ---------------- K4: fused decode: xhat (fp16 Pd stream) + both composites --------
__global__ __launch_bounds__(256, 4) void k_dec(
    const __half* __restrict__ Pd, const float* __restrict__ Dm,
    const float* __restrict__ Am, float* __restrict__ outp)
{
  extern __shared__ float lds[];
  float*  o0 = lds;                                      // 3136 f32
  float*  Da = lds + 3136;                               // 528
  float*  av = lds + 3664;                               // 80
  __half* xh = reinterpret_cast<__half*>(lds + 3744);    // 16*784 halves (25088 B)
  const int b = blockIdx.x;
  const int tid = threadIdx.x;

  for (int idx=tid; idx<512; idx+=256){
    int t = idx >> 5, i = idx & 31;
    Da[t*33 + i] = Dm[((size_t)t*BATCH + b)*32 + i];
  }
  if (tid < 16) Da[tid*33 + 32] = 1.0f;
  if (tid < 80) av[tid] = Am[((size_t)(tid>>2)*BATCH + b)*4 + (tid&3)];

  f32x2 accL[16], accH[16];
  #pragma unroll
  for (int t=0;t<16;t++){
    accL[t].x=0.f; accL[t].y=0.f;
    accH[t].x=0.f; accH[t].y=0.f;
  }
  __syncthreads();

  const __half* Pdb = Pd + (size_t)b*PD_COLS;
  #pragma unroll 3
  for (int i=0;i<33;i++){
    const __half* row = Pdb + (i<32 ? i*784 : 25088);
    f32x2 vlo = {0.f,0.f}, vhi = {0.f,0.f};
    if (tid < 196){
      const __half2 h0 = reinterpret_cast<const __half2*>(row)[tid*2];
      const __half2 h1 = reinterpret_cast<const __half2*>(row)[tid*2+1];
      float2 f0 = __half22float2(h0), f1 = __half22float2(h1);
      vlo.x = f0.x; vlo.y = f0.y; vhi.x = f1.x; vhi.y = f1.y;
    }
    #pragma unroll
    for (int t=0;t<16;t++){
      float da = Da[t*33 + i];
      f32x2 d2; d2.x = da; d2.y = da;
      accL[t] += d2*vlo;
      accH[t] += d2*vhi;
    }
  }
  if (tid < 196){
    #pragma unroll
    for (int t=0;t<16;t++){
      __half2* dst = reinterpret_cast<__half2*>(xh + t*784 + tid*4);
      dst[0] = __floats2half2_rn(accL[t].x, accL[t].y);
      dst[1] = __floats2half2_rn(accH[t].x, accH[t].y);
    }
  }
  __syncthreads();

  // level-0 composite
  for (int idx=tid; idx<4*784; idx+=256){
    int t = idx / 784, pix = idx - t*784;
    int r = pix / 28, c = pix - r*28;
    float s = 0.f;
    #pragma unroll
    for (int k=0;k<4;k++){
      const float* ap = av + (4 + t*4 + k)*4;
      s += bilinh(xh + (t*4+k)*784, ap[0], ap[1], ap[2], ap[3], r, c);
    }
    o0[t*784 + pix] = s;
  }
  __syncthreads();

  // level-1 composite -> d_out
  for (int idx=tid; idx<784; idx+=256){
    int r = idx / 28, c = idx - r*28;
    float s = 0.f;
    #pragma unroll
    for (int t=0;t<4;t++){
      const float* ap = av + t*4;
      s += bilin(o0 + t*784, ap[0], ap[1], ap[2], ap[3], r, c);
    }
    outp[(size_t)b*784 + idx] = s;
  }
}

extern "C" void kernel_launch(void* const* d_in, const int* in_sizes, int n_in,
                              void* d_out, int out_size, void* d_ws, size_t ws_size,
                              hipStream_t stream)
{
  const float* z   = (const float*)d_in[1];
  const float* sw1 = (const float*)d_in[2];
  const float* sb1 = (const float*)d_in[3];
  const float* sw2 = (const float*)d_in[4];
  const float* sb2 = (const float*)d_in[5];
  const float* sw3 = (const float*)d_in[6];
  const float* sb3 = (const float*)d_in[7];
  const float* pw1 = (const float*)d_in[8];
  const float* pb1 = (const float*)d_in[9];
  const float* pw2 = (const float*)d_in[10];
  const float* pb2 = (const float*)d_in[11];
  const float* pw3 = (const float*)d_in[12];
  const float* pb3 = (const float*)d_in[13];

  float* ws = (float*)d_ws;
  float*  Ps = ws;                                   // 1024*10464
  float*  Pp = ws + 10715136;                        // 1024*10596
  __half* Pd = (__half*)(ws + 21565440);             // 1024*25872 halves
  float*  Dm = ws + 34811904;                        // 16*1024*32
  float*  Am = ws + 35336192;                        // 20*1024*4
  unsigned short* h2s_hi = (unsigned short*)(ws + 35418112);   // 1024*64 each
  unsigned short* h2s_lo = h2s_hi + 65536;
  unsigned short* h2p_hi = h2s_hi + 131072;
  unsigned short* h2p_lo = h2s_hi + 196608;
  float* outp = (float*)d_out;

  (void)hipFuncSetAttribute(reinterpret_cast<const void*>(k_dec),
                            hipFuncAttributeMaxDynamicSharedMemorySize,
                            40064);

  hipLaunchKernelGGL(k_backbone, dim3(1024), dim3(128), 0, stream,
                     z, sw1,sb1,sw2,sb2, pw1,pb1,pw2,pb2,
                     h2s_hi, h2s_lo, h2p_hi, h2p_lo);
  hipLaunchKernelGGL(k_params5, dim3(735), dim3(256), 0, stream,
                     h2s_hi, h2s_lo, h2p_hi, h2p_lo,
                     sw3, sb3, pw3, pb3, Ps, Pp, Pd);
  hipLaunchKernelGGL(k_seq2, dim3(1024), dim3(128), 0, stream,
                     Ps, Pp, Dm, Am);
  hipLaunchKernelGGL(k_dec, dim3(1024), dim3(256), 40064, stream,
                     Pd, Dm, Am, outp);
}

// Round 14
// 136.630 us; speedup vs baseline: 1.4938x; 1.0038x over previous
//
#include <hip/hip_runtime.h>
#include <hip/hip_fp16.h>
#include <cmath>

#define BATCH 1024
#define SOUT 36336
#define POUT 10596
#define PS_COLS 10464   // s params compacted (dec2 block removed)
#define PP_COLS 10596
#define PD_COLS 25872   // s dec2 block (W 32x784 + b 784)

typedef __attribute__((ext_vector_type(8))) short bf16x8;
typedef __attribute__((ext_vector_type(4))) float f32x4;
typedef __attribute__((ext_vector_type(2))) float f32x2;

__device__ __forceinline__ float sigmoidf_(float x){ return 1.0f/(1.0f+__expf(-x)); }
__device__ __forceinline__ float reluf_(float x){ return x>0.0f?x:0.0f; }
__device__ __forceinline__ float fast_tanhf(float x){
  float e = __expf(2.f*x);
  return 1.f - 2.f/(e + 1.f);
}

__device__ __forceinline__ void bf16split(float f, unsigned short& hi, unsigned short& lo){
  unsigned u = __float_as_uint(f);
  hi = (unsigned short)(u >> 16);
  float fhi = __uint_as_float(((unsigned)hi) << 16);
  float rem = f - fhi;                       // exact in fp32
  lo = (unsigned short)(__float_as_uint(rem) >> 16);
}

// ---------------- K1: backbone hidden h2 (s and p), emitted as bf16 hi/lo ---------
__global__ __launch_bounds__(128) void k_backbone(
    const float* __restrict__ z,
    const float* __restrict__ sw1, const float* __restrict__ sb1,
    const float* __restrict__ sw2, const float* __restrict__ sb2,
    const float* __restrict__ pw1, const float* __restrict__ pb1,
    const float* __restrict__ pw2, const float* __restrict__ pb2,
    unsigned short* __restrict__ h2s_hi, unsigned short* __restrict__ h2s_lo,
    unsigned short* __restrict__ h2p_hi, unsigned short* __restrict__ h2p_lo)
{
  __shared__ float zsh[32];
  __shared__ float h1sh[2][64];
  const int b = blockIdx.x;
  const int tid = threadIdx.x;
  const int g = tid >> 6, o = tid & 63;
  if (tid < 32) zsh[tid] = z[b*32 + tid];
  __syncthreads();
  const float* w1 = g ? pw1 : sw1;
  const float* b1 = g ? pb1 : sb1;
  float acc = b1[o];
  #pragma unroll
  for (int i=0;i<32;i++) acc += zsh[i]*w1[i*64+o];
  h1sh[g][o] = reluf_(acc);
  __syncthreads();
  const float* w2 = g ? pw2 : sw2;
  const float* b2 = g ? pb2 : sb2;
  float acc2 = b2[o];
  #pragma unroll
  for (int i=0;i<64;i++) acc2 += h1sh[g][i]*w2[i*64+o];
  float v = reluf_(acc2);
  unsigned short hi, lo;
  bf16split(v, hi, lo);
  (g ? h2p_hi : h2s_hi)[b*64+o] = hi;
  (g ? h2p_lo : h2s_lo)[b*64+o] = lo;
}

// ---------------- K2: all three params GEMMs on MFMA (bf16 hi/lo split) -----------
__global__ __launch_bounds__(256, 2) void k_params5(
    const unsigned short* __restrict__ h2s_hi, const unsigned short* __restrict__ h2s_lo,
    const unsigned short* __restrict__ h2p_hi, const unsigned short* __restrict__ h2p_lo,
    const float* __restrict__ sw3, const float* __restrict__ sb3,
    const float* __restrict__ pw3, const float* __restrict__ pb3,
    float* __restrict__ Ps, float* __restrict__ Pp, __half* __restrict__ Pd)
{
  __shared__ __align__(16) unsigned short wth[64][72];   // w3^T hi, padded
  __shared__ __align__(16) unsigned short wtl[64][72];   // w3^T lo
  int xt = blockIdx.x;
  const unsigned short *ahi, *alo;
  const float *w3, *b3;
  float* outF = nullptr; __half* outH = nullptr;
  int OC, thr, off, stride;
  if (xt < 164){
    ahi=h2s_hi; alo=h2s_lo; w3=sw3; b3=sb3; outF=Ps;
    OC=PS_COLS; thr=4192; off=25872; stride=SOUT;
  } else if (xt < 330){
    xt -= 164;
    ahi=h2p_hi; alo=h2p_lo; w3=pw3; b3=pb3; outF=Pp;
    OC=PP_COLS; thr=0x40000000; off=0; stride=POUT;
  } else {
    xt -= 330;
    ahi=h2s_hi; alo=h2s_lo; w3=sw3; b3=sb3; outH=Pd;
    OC=PD_COLS; thr=0; off=4192; stride=SOUT;
  }
  const int c0 = xt*64;
  const int tid = threadIdx.x;

  for (int idx=tid; idx<4096; idx+=256){
    int j = idx >> 6, cc = idx & 63;
    int c = c0 + cc; if (c > OC-1) c = OC-1;
    int src = (c < thr) ? c : c + off;
    float f = w3[(size_t)j*stride + src];
    unsigned short hi, lo;
    bf16split(f, hi, lo);
    wth[cc][j] = hi; wtl[cc][j] = lo;
  }
  __syncthreads();

  const int wv = tid >> 6, l = tid & 63;
  const int lr = l & 15, lq = l >> 4;

  bf16x8 Bh[2][4], Bl[2][4];
  #pragma unroll
  for (int ks=0; ks<2; ks++){
    #pragma unroll
    for (int ct=0; ct<4; ct++){
      const int row = ct*16 + lr;
      const int joff = ks*32 + lq*8;
      Bh[ks][ct] = *reinterpret_cast<const bf16x8*>(&wth[row][joff]);
      Bl[ks][ct] = *reinterpret_cast<const bf16x8*>(&wtl[row][joff]);
    }
  }
  float bv[4];
  #pragma unroll
  for (int ct=0; ct<4; ct++){
    int c = c0 + ct*16 + lr; if (c > OC-1) c = OC-1;
    int src = (c < thr) ? c : c + off;
    bv[ct] = b3[src];
  }

  for (int bsub=0; bsub<16; bsub++){
    const int arow = bsub*64 + wv*16 + lr;
    const unsigned short* ah = ahi + arow*64;
    const unsigned short* al = alo + arow*64;
    bf16x8 Ah0 = *reinterpret_cast<const bf16x8*>(ah + lq*8);
    bf16x8 Ah1 = *reinterpret_cast<const bf16x8*>(ah + 32 + lq*8);
    bf16x8 Al0 = *reinterpret_cast<const bf16x8*>(al + lq*8);
    bf16x8 Al1 = *reinterpret_cast<const bf16x8*>(al + 32 + lq*8);
    #pragma unroll
    for (int ct=0; ct<4; ct++){
      f32x4 acc = {0.f,0.f,0.f,0.f};
      acc = __builtin_amdgcn_mfma_f32_16x16x32_bf16(Ah0, Bh[0][ct], acc, 0,0,0);
      acc = __builtin_amdgcn_mfma_f32_16x16x32_bf16(Ah1, Bh[1][ct], acc, 0,0,0);
      acc = __builtin_amdgcn_mfma_f32_16x16x32_bf16(Ah0, Bl[0][ct], acc, 0,0,0);
      acc = __builtin_amdgcn_mfma_f32_16x16x32_bf16(Ah1, Bl[1][ct], acc, 0,0,0);
      acc = __builtin_amdgcn_mfma_f32_16x16x32_bf16(Al0, Bh[0][ct], acc, 0,0,0);
      acc = __builtin_amdgcn_mfma_f32_16x16x32_bf16(Al1, Bh[1][ct], acc, 0,0,0);
      const int c = c0 + ct*16 + lr;
      if (c < OC){
        const int r0 = bsub*64 + wv*16 + lq*4;
        const float bb = bv[ct];
        if (outF){
          outF[(size_t)(r0+0)*OC + c] = acc[0] + bb;
          outF[(size_t)(r0+1)*OC + c] = acc[1] + bb;
          outF[(size_t)(r0+2)*OC + c] = acc[2] + bb;
          outF[(size_t)(r0+3)*OC + c] = acc[3] + bb;
        } else {
          outH[(size_t)(r0+0)*OC + c] = __float2half(acc[0] + bb);
          outH[(size_t)(r0+1)*OC + c] = __float2half(acc[1] + bb);
          outH[(size_t)(r0+2)*OC + c] = __float2half(acc[2] + bb);
          outH[(size_t)(r0+3)*OC + c] = __float2half(acc[3] + bb);
        }
      }
    }
  }
}

// ---------------- K3: hyper-GRU seq, wave-per-net, register-resident weights ------
// waves_per_eu(2,2): exactly the occupancy we need (2048 waves = 2/SIMD) and a
// 256-VGPR budget so the ~160-float weight set stays in registers (no remat).
// wX packing: lanes <32 hold wR2 (candidate), lanes >=32 hold wK2 (xh).
__global__ __launch_bounds__(128)
__attribute__((amdgpu_waves_per_eu(2, 2)))
void k_seq2(
    const float* __restrict__ Ps, const float* __restrict__ Pp,
    float* __restrict__ Dout, float* __restrict__ Aout)
{
  __shared__ float xvT[64], xvI[64], initZ[64], hst[64];
  __shared__ float psA[128], e2s[64], rhs[64], xhs[64], d1s[32], d2w[132];

  const int b = blockIdx.x;
  const int tid = threadIdx.x;
  const int g = tid >> 6, l = tid & 63;
  const int o = l & 31, h = l >> 5;
  const float* Gp = g ? (Pp + (size_t)b*PP_COLS) : (Ps + (size_t)b*PS_COLS);
  const int rnn = g ? 4324 : 4192;

  f32x2 wE1[16], wED[16], wK[16], wR[16], wX[16];
  float bE1, bED, bK, bK2;

  bE1 = Gp[2048 + o];
  bK  = Gp[rnn + 6144 + l];
  bK2 = Gp[rnn + 6144 + 64 + o];
  const int xb = (l < 32) ? (rnn + 3072) : rnn;   // wR2 : wK2
  #pragma unroll
  for (int i=0;i<16;i++){
    wE1[i].x = Gp[h*1024 + (2*i)*32 + o];   wE1[i].y = Gp[h*1024 + (2*i+1)*32 + o];
    wK[i].x  = Gp[rnn + (2*i)*96 + l];      wK[i].y  = Gp[rnn + (2*i+1)*96 + l];
    wR[i].x  = Gp[rnn + 3072 + (2*i)*96 + l];
    wR[i].y  = Gp[rnn + 3072 + (2*i+1)*96 + l];
    wX[i].x  = Gp[xb + (2*i)*96 + 64 + o];  wX[i].y  = Gp[xb + (2*i+1)*96 + 64 + o];
  }
  if (l < 32){
    #pragma unroll
    for (int i=0;i<16;i++){
      wED[i].x = Gp[2080 + (2*i)*32 + o];  wED[i].y = Gp[2080 + (2*i+1)*32 + o];
    }
    bED = Gp[3104 + o];
  } else {
    #pragma unroll
    for (int i=0;i<16;i++){
      wED[i].x = Gp[3136 + (2*i)*32 + o];  wED[i].y = Gp[3136 + (2*i+1)*32 + o];
    }
    bED = Gp[4160 + o];
  }
  if (g == 1){                          // p dec2 weights -> LDS (tiny)
    for (int idx=l; idx<132; idx+=64) d2w[idx] = Gp[4192 + idx];
  }

  if (tid < 64) hst[tid] = 0.f;
  if (tid < 32) initZ[tid] = Ps[(size_t)b*PS_COLS + 10432 + tid];
  else if (tid < 64) initZ[tid] = Pp[(size_t)b*PP_COLS + 10564 + (tid-32)];
  __syncthreads();
  if (tid < 64) xvT[tid] = initZ[tid];
  __syncthreads();

  auto substep = [&](const float* xv, int aidx, int t16, bool isTop){
    // 1: e1 K-half psums (all lanes)
    {
      f32x2 s0 = {0.f,0.f}, s1 = {0.f,0.f};
      const float4* x4 = reinterpret_cast<const float4*>(&xv[h*32]);
      #pragma unroll
      for (int i=0;i<8;i++){
        float4 v = x4[i];
        f32x2 vlo; vlo.x=v.x; vlo.y=v.y;
        f32x2 vhi; vhi.x=v.z; vhi.y=v.w;
        s0 += vlo*wE1[2*i];
        s1 += vhi*wE1[2*i+1];
      }
      psA[g*64 + l] = (s0.x+s0.y)+(s1.x+s1.y) + ((l<32)?bE1:0.f);
    }
    // 2: e2 = relu(e1) @ Wenc2 + b (lanes 0-31) — psA same-wave, lgkm-ordered
    if (l < 32){
      f32x2 s0 = {0.f,0.f}, s1 = {0.f,0.f};
      const float4* p0 = reinterpret_cast<const float4*>(&psA[g*64]);
      const float4* p1 = reinterpret_cast<const float4*>(&psA[g*64+32]);
      #pragma unroll
      for (int i=0;i<8;i++){
        float4 u = p0[i], v = p1[i];
        f32x2 elo; elo.x=reluf_(u.x+v.x); elo.y=reluf_(u.y+v.y);
        f32x2 ehi; ehi.x=reluf_(u.z+v.z); ehi.y=reluf_(u.w+v.w);
        s0 += elo*wED[2*i];
        s1 += ehi*wED[2*i+1];
      }
      e2s[g*32 + o] = (s0.x+s0.y)+(s1.x+s1.y) + bED;
    }
    // 3: gxh (all lanes); xh col 64+o + r-gate (lanes 32-63)
    float gxh;
    {
      f32x2 k0={0.f,0.f},k1={0.f,0.f},r0={0.f,0.f},r1={0.f,0.f},x0={0.f,0.f},x1={0.f,0.f};
      const float4* e4 = reinterpret_cast<const float4*>(&e2s[g*32]);
      const float4* h4 = reinterpret_cast<const float4*>(&hst[g*32]);
      #pragma unroll
      for (int i=0;i<8;i++){
        float4 u = e4[i], v = h4[i];
        f32x2 ulo; ulo.x=u.x; ulo.y=u.y;
        f32x2 uhi; uhi.x=u.z; uhi.y=u.w;
        f32x2 vlo; vlo.x=v.x; vlo.y=v.y;
        f32x2 vhi; vhi.x=v.z; vhi.y=v.w;
        k0 += ulo*wK[2*i]; k1 += uhi*wK[2*i+1];
        r0 += vlo*wR[2*i]; r1 += vhi*wR[2*i+1];
        x0 += ulo*wX[2*i]; x1 += uhi*wX[2*i+1];   // wX=wK2 on l>=32 (valid there)
      }
      gxh = (k0.x+k0.y)+(k1.x+k1.y) + bK + (r0.x+r0.y)+(r1.x+r1.y);
      if (l >= 32){
        xhs[g*32 + o] = (x0.x+x0.y)+(x1.x+x1.y) + bK2;
        float rg = sigmoidf_(gxh);
        rhs[g*32 + o] = rg * hst[g*32 + o];
      }
    }
    // 5: z-gate + candidate + h-update (lanes 0-31); wX=wR2 here
    if (l < 32){
      float zg = sigmoidf_(gxh);
      f32x2 s0 = {0.f,0.f}, s1 = {0.f,0.f};
      const float4* r4 = reinterpret_cast<const float4*>(&rhs[g*32]);
      #pragma unroll
      for (int i=0;i<8;i++){
        float4 v = r4[i];
        f32x2 vlo; vlo.x=v.x; vlo.y=v.y;
        f32x2 vhi; vhi.x=v.z; vhi.y=v.w;
        s0 += vlo*wX[2*i];
        s1 += vhi*wX[2*i+1];
      }
      float hh = fast_tanhf(xhs[g*32+o] + (s0.x+s0.y)+(s1.x+s1.y));
      float ho = hst[g*32+o];
      float hn = zg*ho + (1.f-zg)*hh;
      hst[g*32+o] = hn;
      if (isTop){ xvT[g*32+o] = hn; xvI[g*32+o] = initZ[g*32+o]; }
      else        xvI[g*32+o] = hn;
    }
    // 6: dec1 (lanes 32-63) on NEW h — same-wave ordering
    if (l >= 32 && (g==1 || t16 >= 0)){
      f32x2 s0 = {0.f,0.f}, s1 = {0.f,0.f};
      const float4* h4 = reinterpret_cast<const float4*>(&hst[g*32]);
      #pragma unroll
      for (int i=0;i<8;i++){
        float4 v = h4[i];
        f32x2 vlo; vlo.x=v.x; vlo.y=v.y;
        f32x2 vhi; vhi.x=v.z; vhi.y=v.w;
        s0 += vlo*wED[2*i];
        s1 += vhi*wED[2*i+1];
      }
      float d = reluf_((s0.x+s0.y)+(s1.x+s1.y) + bED);
      if (g == 0) Dout[((size_t)t16*BATCH + b)*32 + o] = d;
      else d1s[o] = d;
    }
    // 7: p dec2 -> a (wave1 lanes 32-35), weights from LDS
    if (g == 1 && l >= 32 && l < 36){
      const int c = l - 32;
      float acc = d2w[128 + c];
      #pragma unroll
      for (int i=0;i<32;i++) acc += d1s[i]*d2w[i*4 + c];
      Aout[((size_t)aidx*BATCH + b)*4 + c] = acc;
    }
    __syncthreads();   // xvT/xvI visible to the other wave
  };

  for (int t=0;t<4;t++){
    substep(xvT, t, -1, true);
    for (int k=0;k<4;k++){
      substep(xvI, 4 + t*4 + k, t*4 + k, false);
    }
  }
}

// ---------------- bilinear samplers (fp32 and fp16 LDS images) ----------------
__device__ __forceinline__ float fetchpix(const float* __restrict__ img, int y, int x){
  if ((unsigned)y >= 28u || (unsigned)x >= 28u) return 0.0f;
  return img[y*28 + x];
}
__device__ __forceinline__ float fetchpixh(const __half* __restrict__ img, int y, int x){
  if ((unsigned)y >= 28u || (unsigned)x >= 28u) return 0.0f;
  return __half2float(img[y*28 + x]);
}
#define BILIN_BODY(FETCH) \
  const float stepv = 2.0f/27.0f; \
  float gxv = -1.0f + stepv*(float)c; \
  float gyv = -1.0f + stepv*(float)r; \
  float srcx = (a0 + 1.0f)*gxv + a2; \
  float srcy = (a1 + 1.0f)*gyv + a3; \
  float px = (srcx + 1.0f)*13.5f; \
  float py = (srcy + 1.0f)*13.5f; \
  float x0f = floorf(px), y0f = floorf(py); \
  float wx = px - x0f, wy = py - y0f; \
  int x0 = (int)x0f, y0 = (int)y0f; \
  float v00 = FETCH(img, y0,   x0); \
  float v01 = FETCH(img, y0,   x0+1); \
  float v10 = FETCH(img, y0+1, x0); \
  float v11 = FETCH(img, y0+1, x0+1); \
  return v00*(1.0f-wx)*(1.0f-wy) + v01*wx*(1.0f-wy) \
       + v10*(1.0f-wx)*wy + v11*wx*wy;

__device__ __forceinline__ float bilin(const float* __restrict__ img,
    float a0, float a1, float a2, float a3, int r, int c){ BILIN_BODY(fetchpix) }
__device__ __forceinline__ float bilinh(const __half* __restrict__ img,
    float a0, float a1, float a2, float a3, int r, int c){ BILIN_BODY(fetchpixh) }

// ---------------- K4: fused decode: xhat (fp16 Pd stream) + both composites --------
__global__ __launch_bounds__(256, 4) void k_dec(
    const __half* __restrict__ Pd, const float* __restrict__ Dm,
    const float* __restrict__ Am, float* __restrict__ outp)
{
  extern __shared__ float lds[];
  float*  o0 = lds;                                      // 3136 f32
  float*  Da = lds + 3136;                               // 528
  float*  av = lds + 3664;                               // 80
  __half* xh = reinterpret_cast<__half*>(lds + 3744);    // 16*784 halves (25088 B)
  const int b = blockIdx.x;
  const int tid = threadIdx.x;

  for (int idx=tid; idx<512; idx+=256){
    int t = idx >> 5, i = idx & 31;
    Da[t*33 + i] = Dm[((size_t)t*BATCH + b)*32 + i];
  }
  if (tid < 16) Da[tid*33 + 32] = 1.0f;
  if (tid < 80) av[tid] = Am[((size_t)(tid>>2)*BATCH + b)*4 + (tid&3)];

  f32x2 accL[16], accH[16];
  #pragma unroll
  for (int t=0;t<16;t++){
    accL[t].x=0.f; accL[t].y=0.f;
    accH[t].x=0.f; accH[t].y=0.f;
  }
  __syncthreads();

  const __half* Pdb = Pd + (size_t)b*PD_COLS;
  #pragma unroll 3
  for (int i=0;i<33;i++){
    const __half* row = Pdb + (i<32 ? i*784 : 25088);
    f32x2 vlo = {0.f,0.f}, vhi = {0.f,0.f};
    if (tid < 196){
      const __half2 h0 = reinterpret_cast<const __half2*>(row)[tid*2];
      const __half2 h1 = reinterpret_cast<const __half2*>(row)[tid*2+1];
      float2 f0 = __half22float2(h0), f1 = __half22float2(h1);
      vlo.x = f0.x; vlo.y = f0.y; vhi.x = f1.x; vhi.y = f1.y;
    }
    #pragma unroll
    for (int t=0;t<16;t++){
      float da = Da[t*33 + i];
      f32x2 d2; d2.x = da; d2.y = da;
      accL[t] += d2*vlo;
      accH[t] += d2*vhi;
    }
  }
  if (tid < 196){
    #pragma unroll
    for (int t=0;t<16;t++){
      __half2* dst = reinterpret_cast<__half2*>(xh + t*784 + tid*4);
      dst[0] = __floats2half2_rn(accL[t].x, accL[t].y);
      dst[1] = __floats2half2_rn(accH[t].x, accH[t].y);
    }
  }
  __syncthreads();

  // level-0 composite
  for (int idx=tid; idx<4*784; idx+=256){
    int t = idx / 784, pix = idx - t*784;
    int r = pix / 28, c = pix - r*28;
    float s = 0.f;
    #pragma unroll
    for (int k=0;k<4;k++){
      const float* ap = av + (4 + t*4 + k)*4;
      s += bilinh(xh + (t*4+k)*784, ap[0], ap[1], ap[2], ap[3], r, c);
    }
    o0[t*784 + pix] = s;
  }
  __syncthreads();

  // level-1 composite -> d_out
  for (int idx=tid; idx<784; idx+=256){
    int r = idx / 28, c = idx - r*28;
    float s = 0.f;
    #pragma unroll
    for (int t=0;t<4;t++){
      const float* ap = av + t*4;
      s += bilin(o0 + t*784, ap[0], ap[1], ap[2], ap[3], r, c);
    }
    outp[(size_t)b*784 + idx] = s;
  }
}

extern "C" void kernel_launch(void* const* d_in, const int* in_sizes, int n_in,
                              void* d_out, int out_size, void* d_ws, size_t ws_size,
                              hipStream_t stream)
{
  const float* z   = (const float*)d_in[1];
  const float* sw1 = (const float*)d_in[2];
  const float* sb1 = (const float*)d_in[3];
  const float* sw2 = (const float*)d_in[4];
  const float* sb2 = (const float*)d_in[5];
  const float* sw3 = (const float*)d_in[6];
  const float* sb3 = (const float*)d_in[7];
  const float* pw1 = (const float*)d_in[8];
  const float* pb1 = (const float*)d_in[9];
  const float* pw2 = (const float*)d_in[10];
  const float* pb2 = (const float*)d_in[11];
  const float* pw3 = (const float*)d_in[12];
  const float* pb3 = (const float*)d_in[13];

  float* ws = (float*)d_ws;
  float*  Ps = ws;                                   // 1024*10464
  float*  Pp = ws + 10715136;                        // 1024*10596
  __half* Pd = (__half*)(ws + 21565440);             // 1024*25872 halves
  float*  Dm = ws + 34811904;                        // 16*1024*32
  float*  Am = ws + 35336192;                        // 20*1024*4
  unsigned short* h2s_hi = (unsigned short*)(ws + 35418112);   // 1024*64 each
  unsigned short* h2s_lo = h2s_hi + 65536;
  unsigned short* h2p_hi = h2s_hi + 131072;
  unsigned short* h2p_lo = h2s_hi + 196608;
  float* outp = (float*)d_out;

  (void)hipFuncSetAttribute(reinterpret_cast<const void*>(k_dec),
                            hipFuncAttributeMaxDynamicSharedMemorySize,
                            40064);

  hipLaunchKernelGGL(k_backbone, dim3(1024), dim3(128), 0, stream,
                     z, sw1,sb1,sw2,sb2, pw1,pb1,pw2,pb2,
                     h2s_hi, h2s_lo, h2p_hi, h2p_lo);
  hipLaunchKernelGGL(k_params5, dim3(735), dim3(256), 0, stream,
                     h2s_hi, h2s_lo, h2p_hi, h2p_lo,
                     sw3, sb3, pw3, pb3, Ps, Pp, Pd);
  hipLaunchKernelGGL(k_seq2, dim3(1024), dim3(128), 0, stream,
                     Ps, Pp, Dm, Am);
  hipLaunchKernelGGL(k_dec, dim3(1024), dim3(256), 40064, stream,
                     Pd, Dm, Am, outp);
}